// Round 3
// baseline (4706.764 us; speedup 1.0000x reference)
//
#include <hip/hip_runtime.h>
#include <math.h>

#define D   32
#define FIN 16
#define KH  128
#define NW  1024
#define BM  64
#define BN  64
#define BK  64
#define BNP 68

__device__ __forceinline__ double dsig(double x){ return 1.0/(1.0+exp(-x)); }

// ---------------- degree / inv_deg ----------------
__global__ void k_deg(const int* __restrict__ dst, int* __restrict__ deg, int E){
    int e = blockIdx.x*256 + threadIdx.x;
    if (e < E) atomicAdd(&deg[dst[e]], 1);
}
__global__ void k_invdeg(const int* __restrict__ deg, float* __restrict__ invd, int n){
    int i = blockIdx.x*256 + threadIdx.x;
    if (i < n) { int d = deg[i]; invd[i] = (d > 0) ? (1.0f/(float)d) : 0.0f; }
}

// ---------------- transpose LSTM / lin1 weights for coalesced reads ----------------
__global__ void k_tposew(const float* __restrict__ wih, const float* __restrict__ whh,
                         const float* __restrict__ l1w,
                         float* __restrict__ wihT, float* __restrict__ whhT,
                         float* __restrict__ l1T){
    int t = blockIdx.x*256 + threadIdx.x;
    if (t < 128*64) { int j = t/64, i = t%64; wihT[i*128+j] = wih[t]; l1T[i*128+j] = l1w[t]; }
    if (t < 128*32) { int j = t/32, i = t%32; whhT[i*128+j] = whh[t]; }
}

// ---------------- lin0 + relu ----------------
__global__ __launch_bounds__(256) void k_lin0(const float* __restrict__ x,
    const float* __restrict__ w, const float* __restrict__ b,
    float* __restrict__ out, int n){
    __shared__ float wT[FIN*33];   // wT[i*33+o]
    __shared__ float sb[D];
    int t = threadIdx.x;
    // FIX: D*FIN = 512 > blockDim (256) — must stride, not mask.
    for (int idx = t; idx < D*FIN; idx += 256) {
        int o = idx/FIN, i = idx%FIN; wT[i*33+o] = w[idx];
    }
    if (t < D) sb[t] = b[t];
    __syncthreads();
    int g = t >> 5, o = t & 31;
    int node = blockIdx.x*8 + g;
    if (node >= n) return;
    float xo = (o < FIN) ? x[node*FIN + o] : 0.0f;
    double acc = (double)sb[o];
    #pragma unroll
    for (int i = 0; i < FIN; ++i) {
        float xi = __shfl(xo, i, 32);
        acc += (double)xi * (double)wT[i*33+o];
    }
    out[node*D + o] = fmaxf((float)acc, 0.0f);
}

// ---------------- edge network GEMM for edges [e_base, e_base+e_cnt):
//   We[(e-e_base), i*32+o] = (relu(attr@w1^T+b1) @ w2^T + b2)  ----------------
__global__ __launch_bounds__(256) void k_we(
    const float* __restrict__ attr, const float* __restrict__ w1,
    const float* __restrict__ b1, const float* __restrict__ w2,
    const float* __restrict__ b2, float* __restrict__ We,
    int e_base, int e_cnt){
    __shared__ alignas(16) float As[BK][BM];    // [k][m]
    __shared__ alignas(16) float Bs[BK][BNP];   // [k][n]
    __shared__ float sattr[BM*3];
    __shared__ float sw1[3*KH];                 // [j][k]
    __shared__ float sb1[KH];
    int t  = threadIdx.x;
    int e0 = e_base + blockIdx.x * BM;          // global edge id of row 0
    int e_end = e_base + e_cnt;
    int n0 = blockIdx.y * BN;
    if (t < BM*3) {
        int e = e0 + t/3;
        sattr[t] = (e < e_end) ? attr[(size_t)e0*3 + t] : 0.0f;
    }
    // FIX: 3*KH = 384 > blockDim (256) — must stride, not mask.
    for (int idx = t; idx < 3*KH; idx += 256) {
        int k = idx/3, j = idx%3; sw1[j*KH + k] = w1[idx];
    }
    if (t < KH) sb1[t] = b1[t];
    __syncthreads();

    int tx = t & 15, ty = t >> 4;
    float acc[4][4] = {};
    for (int kc = 0; kc < KH; kc += BK) {
        #pragma unroll
        for (int p = 0; p < (BM*BK)/256; ++p) {
            int idx = p*256 + t;
            int m = idx & (BM-1), k = idx >> 6;
            int kg = kc + k;
            float v = sb1[kg] + sattr[m*3+0]*sw1[kg]
                              + sattr[m*3+1]*sw1[KH+kg]
                              + sattr[m*3+2]*sw1[2*KH+kg];
            As[k][m] = ((e0 + m) < e_end) ? fmaxf(v, 0.0f) : 0.0f;
        }
        #pragma unroll
        for (int p = 0; p < (BN*BK)/256; ++p) {
            int idx = p*256 + t;
            int nn = idx >> 6, k = idx & (BK-1);
            Bs[k][nn] = w2[(size_t)(n0+nn)*KH + kc + k];
        }
        __syncthreads();
        #pragma unroll 8
        for (int k = 0; k < BK; ++k) {
            float4 a = *reinterpret_cast<const float4*>(&As[k][ty*4]);
            float4 b = *reinterpret_cast<const float4*>(&Bs[k][tx*4]);
            float av[4] = {a.x,a.y,a.z,a.w};
            float bv[4] = {b.x,b.y,b.z,b.w};
            #pragma unroll
            for (int r = 0; r < 4; ++r)
                #pragma unroll
                for (int c = 0; c < 4; ++c)
                    acc[r][c] += av[r]*bv[c];
        }
        __syncthreads();
    }
    #pragma unroll
    for (int r = 0; r < 4; ++r) {
        int e = e0 + ty*4 + r;
        if (e < e_end) {
            int col = n0 + tx*4;
            float4 o4;
            o4.x = acc[r][0] + b2[col+0];
            o4.y = acc[r][1] + b2[col+1];
            o4.z = acc[r][2] + b2[col+2];
            o4.w = acc[r][3] + b2[col+3];
            *reinterpret_cast<float4*>(&We[(size_t)(e - e_base)*NW + col]) = o4;
        }
    }
}

// ---------------- message for edges [e_base, e_base+e_cnt):
//   msg[e,o] = sum_i out[src,i]*We[e-e_base,i,o]; atomic scatter ----------------
__global__ __launch_bounds__(256) void k_msg(const float* __restrict__ out,
    const float* __restrict__ We, const int* __restrict__ src,
    const int* __restrict__ dst, float* __restrict__ agg,
    int e_base, int e_cnt){
    int t = threadIdx.x;
    int e = e_base + blockIdx.x*8 + (t >> 5);
    int o = t & 31;
    if (e >= e_base + e_cnt) return;
    int s = src[e];
    float vo = out[(size_t)s*D + o];
    const float* W = We + (size_t)(e - e_base)*NW;
    float msg = 0.0f;
    #pragma unroll
    for (int i = 0; i < D; ++i) {
        float vi = __shfl(vo, i, 32);
        msg += vi * W[i*D + o];
    }
    atomicAdd(&agg[(size_t)dst[e]*D + o], msg);
}

// ---------------- scatter-mean finish + root + relu + GRU (in place on out==h) ----------------
__global__ __launch_bounds__(256) void k_gru(float* __restrict__ out,
    const float* __restrict__ agg, const float* __restrict__ invd,
    const float* __restrict__ root_w, const float* __restrict__ conv_b,
    const float* __restrict__ wih, const float* __restrict__ whh,
    const float* __restrict__ bih, const float* __restrict__ bhh, int n){
    __shared__ float srw[D*D];        // root_w [i*32+j]
    __shared__ float swihT[D*97];     // [i*97+j] j<96
    __shared__ float swhhT[D*97];
    __shared__ float scb[D], sbih[96], sbhh[96];
    int t = threadIdx.x;
    for (int idx = t; idx < D*D; idx += 256) srw[idx] = root_w[idx];
    for (int idx = t; idx < 96*D; idx += 256) { int j = idx/D, i = idx%D; swihT[i*97+j] = wih[idx]; }
    for (int idx = t; idx < 96*D; idx += 256) { int j = idx/D, i = idx%D; swhhT[i*97+j] = whh[idx]; }
    if (t < D) scb[t] = conv_b[t];
    if (t < 96) { sbih[t] = bih[t]; sbhh[t] = bhh[t]; }
    __syncthreads();
    int g = t >> 5, o = t & 31;
    int node = blockIdx.x*8 + g;
    if (node >= n) return;
    float ho = out[(size_t)node*D + o];
    double acc = (double)agg[(size_t)node*D + o]*(double)invd[node] + (double)scb[o];
    #pragma unroll
    for (int i = 0; i < D; ++i) acc += (double)__shfl(ho, i, 32)*(double)srw[i*D + o];
    float m = fmaxf((float)acc, 0.0f);
    double gi0 = sbih[o], gi1 = sbih[o+32], gi2 = sbih[o+64];
    double gh0 = sbhh[o], gh1 = sbhh[o+32], gh2 = sbhh[o+64];
    #pragma unroll
    for (int i = 0; i < D; ++i) {
        float mi = __shfl(m, i, 32), hi = __shfl(ho, i, 32);
        gi0 += (double)mi*(double)swihT[i*97+o];    gh0 += (double)hi*(double)swhhT[i*97+o];
        gi1 += (double)mi*(double)swihT[i*97+o+32]; gh1 += (double)hi*(double)swhhT[i*97+o+32];
        gi2 += (double)mi*(double)swihT[i*97+o+64]; gh2 += (double)hi*(double)swhhT[i*97+o+64];
    }
    double r  = dsig(gi0+gh0);
    double z  = dsig(gi1+gh1);
    double ng = tanh(gi2 + r*gh2);
    out[(size_t)node*D + o] = (float)((1.0 - z)*ng + z*(double)ho);
}

// ---------------- Set2Set (3 steps) + lin1/lin2 readout; one block per graph ----------------
__global__ __launch_bounds__(64) void k_s2s(const float* __restrict__ out,
    const float* __restrict__ wihT, const float* __restrict__ whhT,
    const float* __restrict__ bih, const float* __restrict__ bhh,
    const float* __restrict__ l1T, const float* __restrict__ l1b,
    const float* __restrict__ l2w, const float* __restrict__ l2b,
    float* __restrict__ dpred, float* __restrict__ demb, int n, int ngr){
    int b = blockIdx.x, t = threadIdx.x;
    int start = (int)(((long long)b*n + ngr - 1)/ngr);
    int end   = (int)(((long long)(b+1)*n + ngr - 1)/ngr);
    if (end > n) end = n;
    int cnt = end - start;              // 24 or 25 for these sizes
    __shared__ double qs[2*D];
    __shared__ double hhv[D], ccv[D], qv[D];
    __shared__ double gate[4*D];
    __shared__ double ea[40];
    __shared__ double red[2];
    if (t < 2*D) qs[t] = 0.0;
    if (t < D) { hhv[t] = 0.0; ccv[t] = 0.0; }
    __syncthreads();
    for (int step = 0; step < 3; ++step) {
        double g1 = (double)bih[t] + (double)bhh[t];
        double g2 = (double)bih[t+64] + (double)bhh[t+64];
        for (int i = 0; i < 2*D; ++i) {
            double q = qs[i];
            g1 += q * (double)wihT[i*128 + t];
            g2 += q * (double)wihT[i*128 + t + 64];
        }
        for (int i = 0; i < D; ++i) {
            double h = hhv[i];
            g1 += h * (double)whhT[i*128 + t];
            g2 += h * (double)whhT[i*128 + t + 64];
        }
        gate[t] = g1; gate[t+64] = g2;
        __syncthreads();
        if (t < D) {
            double ig = dsig(gate[t]);
            double fg = dsig(gate[D+t]);
            double gg = tanh(gate[2*D+t]);
            double og = dsig(gate[3*D+t]);
            double c  = fg*ccv[t] + ig*gg;
            ccv[t] = c;
            double h = og*tanh(c);
            hhv[t] = h;
            qv[t]  = h;
        }
        __syncthreads();
        if (t < cnt) {
            const float* orow = out + (size_t)(start+t)*D;
            double e = 0.0;
            #pragma unroll
            for (int o = 0; o < D; ++o) e += (double)orow[o]*qv[o];
            ea[t] = e;
        }
        __syncthreads();
        if (t == 0) {
            double mx = -1e300;
            for (int i = 0; i < cnt; ++i) mx = fmax(mx, ea[i]);
            red[0] = mx;
        }
        __syncthreads();
        if (t < cnt) ea[t] = exp(ea[t] - red[0]);
        __syncthreads();
        if (t == 0) {
            double s = 0.0;
            for (int i = 0; i < cnt; ++i) s += ea[i];
            red[1] = s;
        }
        __syncthreads();
        if (t < cnt) ea[t] = ea[t]/red[1];
        __syncthreads();
        if (t < D) {
            double acc = 0.0;
            for (int i = 0; i < cnt; ++i) acc += ea[i]*(double)out[(size_t)(start+i)*D + t];
            qs[t]   = qv[t];
            qs[D+t] = acc;
        }
        __syncthreads();
    }
    double ge1 = l1b[t], ge2 = l1b[t+64];
    for (int i = 0; i < 2*D; ++i) {
        double q = qs[i];
        ge1 += q*(double)l1T[i*128 + t];
        ge2 += q*(double)l1T[i*128 + t + 64];
    }
    demb[(size_t)b*128 + t]      = (float)ge1;
    demb[(size_t)b*128 + t + 64] = (float)ge2;
    double p = fmax(ge1, 0.0)*(double)l2w[t] + fmax(ge2, 0.0)*(double)l2w[t+64];
    #pragma unroll
    for (int off = 32; off > 0; off >>= 1) {
        double other = __shfl_down(p, off, 64);
        p += other;
    }
    if (t == 0) dpred[b] = (float)(p + (double)l2b[0]);
}

extern "C" void kernel_launch(void* const* d_in, const int* in_sizes, int n_in,
                              void* d_out, int out_size, void* d_ws, size_t ws_size,
                              hipStream_t stream) {
    const float* x       = (const float*)d_in[0];
    const float* eattr   = (const float*)d_in[1];
    const float* lin0_w  = (const float*)d_in[2];
    const float* lin0_b  = (const float*)d_in[3];
    const float* enn_w1  = (const float*)d_in[4];
    const float* enn_b1  = (const float*)d_in[5];
    const float* enn_w2  = (const float*)d_in[6];
    const float* enn_b2  = (const float*)d_in[7];
    const float* root_w  = (const float*)d_in[8];
    const float* conv_b  = (const float*)d_in[9];
    const float* gru_wih = (const float*)d_in[10];
    const float* gru_whh = (const float*)d_in[11];
    const float* gru_bih = (const float*)d_in[12];
    const float* gru_bhh = (const float*)d_in[13];
    const float* lstm_wih= (const float*)d_in[14];
    const float* lstm_whh= (const float*)d_in[15];
    const float* lstm_bih= (const float*)d_in[16];
    const float* lstm_bhh= (const float*)d_in[17];
    const float* lin1_w  = (const float*)d_in[18];
    const float* lin1_b  = (const float*)d_in[19];
    const float* lin2_w  = (const float*)d_in[20];
    const float* lin2_b  = (const float*)d_in[21];
    const int*   eidx    = (const int*)d_in[22];

    int N = in_sizes[0]/FIN;     // 100000
    int E = in_sizes[1]/3;       // 300000
    int B = 4096;
    const int* src = eidx;
    const int* dst = eidx + E;

    // ---- workspace layout: small fixed buffers FIRST, We sized from what remains ----
    char* ws = (char*)d_ws;
    size_t off = 0;
    auto alloc = [&](size_t bytes)->void* {
        void* p = ws + off; off += (bytes + 255) & ~(size_t)255; return p;
    };
    float* outb = (float*)alloc((size_t)N*D*sizeof(float));      // 12.8 MB
    float* agg  = (float*)alloc((size_t)N*D*sizeof(float));      // 12.8 MB
    float* invd = (float*)alloc((size_t)N*sizeof(float));
    int*   deg  = (int*)  alloc((size_t)N*sizeof(int));
    float* wihT = (float*)alloc((size_t)128*64*sizeof(float));
    float* whhT = (float*)alloc((size_t)128*32*sizeof(float));
    float* l1T  = (float*)alloc((size_t)128*64*sizeof(float));
    size_t avail = (ws_size > off) ? (ws_size - off) : 0;
    long long cap = (long long)(avail / ((size_t)NW*sizeof(float)));  // edges that fit
    cap = (cap / BM) * BM;
    if (cap < BM) cap = BM;            // last-resort; assumes ws >= ~27 MB
    float* We = (float*)(ws + off);
    (void)n_in; (void)out_size;

    hipMemsetAsync(deg, 0, (size_t)N*sizeof(int), stream);
    k_deg<<<(E+255)/256, 256, 0, stream>>>(dst, deg, E);
    k_invdeg<<<(N+255)/256, 256, 0, stream>>>(deg, invd, N);
    k_tposew<<<32, 256, 0, stream>>>(lstm_wih, lstm_whh, lin1_w, wihT, whhT, l1T);
    k_lin0<<<(N+7)/8, 256, 0, stream>>>(x, lin0_w, lin0_b, outb, N);

    if (cap >= E) {
        // Path A: materialize We once, reuse across the 3 iterations.
        dim3 gwe((E+BM-1)/BM, NW/BN);
        k_we<<<gwe, 256, 0, stream>>>(eattr, enn_w1, enn_b1, enn_w2, enn_b2, We, 0, E);
        for (int it = 0; it < 3; ++it) {
            hipMemsetAsync(agg, 0, (size_t)N*D*sizeof(float), stream);
            k_msg<<<(E+7)/8, 256, 0, stream>>>(outb, We, src, dst, agg, 0, E);
            k_gru<<<(N+7)/8, 256, 0, stream>>>(outb, agg, invd, root_w, conv_b,
                                               gru_wih, gru_whh, gru_bih, gru_bhh, N);
        }
    } else {
        // Path B: ws too small for full We — recompute per chunk per iteration.
        int chunk = (int)cap;
        for (int it = 0; it < 3; ++it) {
            hipMemsetAsync(agg, 0, (size_t)N*D*sizeof(float), stream);
            for (int eb = 0; eb < E; eb += chunk) {
                int ec = (E - eb < chunk) ? (E - eb) : chunk;
                dim3 gwe((ec+BM-1)/BM, NW/BN);
                k_we<<<gwe, 256, 0, stream>>>(eattr, enn_w1, enn_b1, enn_w2, enn_b2, We, eb, ec);
                k_msg<<<(ec+7)/8, 256, 0, stream>>>(outb, We, src, dst, agg, eb, ec);
            }
            k_gru<<<(N+7)/8, 256, 0, stream>>>(outb, agg, invd, root_w, conv_b,
                                               gru_wih, gru_whh, gru_bih, gru_bhh, N);
        }
    }

    float* dpred = (float*)d_out;
    float* demb  = (float*)d_out + B;
    k_s2s<<<B, 64, 0, stream>>>(outb, wihT, whhT, lstm_bih, lstm_bhh,
                                l1T, lin1_b, lin2_w, lin2_b, dpred, demb, N, B);
}

// Round 4
// 1093.168 us; speedup vs baseline: 4.3056x; 4.3056x over previous
//
#include <hip/hip_runtime.h>
#include <math.h>

#define D   32
#define FIN 16
#define KH  128
#define NW  1024

typedef __attribute__((ext_vector_type(8)))  short short8;
typedef __attribute__((ext_vector_type(16))) float f32x16;

__device__ __forceinline__ float sigf(float x){ return 1.0f/(1.0f+expf(-x)); }
__device__ __forceinline__ double dsig(double x){ return 1.0/(1.0+exp(-x)); }
__device__ __forceinline__ short f2bf(float f){ __bf16 h = (__bf16)f; return __builtin_bit_cast(short, h); }
__device__ __forceinline__ float bf2f(short s){ return (float)__builtin_bit_cast(__bf16, s); }

// ---------------- degree / inv_deg ----------------
__global__ void k_deg(const int* __restrict__ dst, int* __restrict__ deg, int E){
    int e = blockIdx.x*256 + threadIdx.x;
    if (e < E) atomicAdd(&deg[dst[e]], 1);
}
__global__ void k_invdeg(const int* __restrict__ deg, float* __restrict__ invd, int n){
    int i = blockIdx.x*256 + threadIdx.x;
    if (i < n) { int d = deg[i]; invd[i] = (d > 0) ? (1.0f/(float)d) : 0.0f; }
}

// ---------------- transpose LSTM / lin1 weights ----------------
__global__ void k_tposew(const float* __restrict__ wih, const float* __restrict__ whh,
                         const float* __restrict__ l1w,
                         float* __restrict__ wihT, float* __restrict__ whhT,
                         float* __restrict__ l1T){
    int t = blockIdx.x*256 + threadIdx.x;
    if (t < 128*64) { int j = t/64, i = t%64; wihT[i*128+j] = wih[t]; l1T[i*128+j] = l1w[t]; }
    if (t < 128*32) { int j = t/32, i = t%32; whhT[i*128+j] = whh[t]; }
}

// ---------------- lin0 + relu ----------------
__global__ __launch_bounds__(256) void k_lin0(const float* __restrict__ x,
    const float* __restrict__ w, const float* __restrict__ b,
    float* __restrict__ out, int n){
    __shared__ float wT[FIN*33];
    __shared__ float sb[D];
    int t = threadIdx.x;
    for (int idx = t; idx < D*FIN; idx += 256) {
        int o = idx/FIN, i = idx%FIN; wT[i*33+o] = w[idx];
    }
    if (t < D) sb[t] = b[t];
    __syncthreads();
    int g = t >> 5, o = t & 31;
    int node = blockIdx.x*8 + g;
    if (node >= n) return;
    float xo = (o < FIN) ? x[node*FIN + o] : 0.0f;
    double acc = (double)sb[o];
    #pragma unroll
    for (int i = 0; i < FIN; ++i) {
        float xi = __shfl(xo, i, 32);
        acc += (double)xi * (double)wT[i*33+o];
    }
    out[node*D + o] = fmaxf((float)acc, 0.0f);
}

// ---------------- ehid in MFMA-fragment-major bf16 layout ----------------
// frag slot f = (te*8 + kt)*64 + lane ; element j of slot f holds
// ehid[e = te*32 + (lane&31)][k = kt*16 + (lane>>5)*8 + j]
__global__ __launch_bounds__(256) void k_ehidf(const float* __restrict__ attr,
    const float* __restrict__ w1, const float* __restrict__ b1,
    short* __restrict__ ehidF, int E, int nte){
    int f = blockIdx.x*256 + threadIdx.x;
    if (f >= nte*512) return;
    int l = f & 63, kt = (f >> 6) & 7, te = f >> 9;
    int e = te*32 + (l & 31);
    int k0 = kt*16 + (l >> 5)*8;
    float a0=0.f, a1=0.f, a2=0.f;
    if (e < E) { a0 = attr[(size_t)e*3]; a1 = attr[(size_t)e*3+1]; a2 = attr[(size_t)e*3+2]; }
    short8 v;
    #pragma unroll
    for (int j = 0; j < 8; ++j) {
        int k = k0 + j;
        float t = b1[k] + a0*w1[k*3] + a1*w1[k*3+1] + a2*w1[k*3+2];
        v[j] = f2bf(fmaxf(t, 0.0f));
    }
    *reinterpret_cast<short8*>(ehidF + (size_t)f*8) = v;
}

// ---------------- w2 in MFMA-fragment-major bf16 layout (B operand) ----------------
// slot f = (tn*8 + kt)*64 + lane ; element j holds w2[n = tn*32 + (lane&31)][k = kt*16 + (lane>>5)*8 + j]
__global__ __launch_bounds__(256) void k_w2f(const float* __restrict__ w2, short* __restrict__ w2F){
    int f = blockIdx.x*256 + threadIdx.x;
    if (f >= 32*8*64) return;
    int l = f & 63, kt = (f >> 6) & 7, tn = f >> 9;
    int n = tn*32 + (l & 31);
    int k0 = kt*16 + (l >> 5)*8;
    short8 v;
    #pragma unroll
    for (int j = 0; j < 8; ++j) v[j] = f2bf(w2[n*KH + k0 + j]);
    *reinterpret_cast<short8*>(w2F + (size_t)f*8) = v;
}

// ---------------- fused NNConv: We tile (MFMA) -> LDS -> per-edge matvec -> atomic scatter ----
// one block = 32 edges; 16 waves; wave w computes cols [w*64, w*64+64) of We (32x1024),
// then wave w does msg for edges w*2 (lanes<32) and w*2+1 (lanes>=32).
#define WEPITCH 1032
__global__ __launch_bounds__(1024) void k_fused(
    const short* __restrict__ ehidF, const short* __restrict__ w2F,
    const float* __restrict__ b2, const float* __restrict__ nodef,
    const int* __restrict__ src, const int* __restrict__ dst,
    float* __restrict__ agg, int E){
    __shared__ short WeL[32*WEPITCH];    // 66 KB, row pitch 1032 breaks bank alias
    int tid = threadIdx.x;
    int w = tid >> 6, l = tid & 63;
    int te = blockIdx.x;
    int col = l & 31, hi = l >> 5;

    // ---- GEMM phase: acc(32x64 slice) = ehid(32x128) @ w2^T(128x1024) cols [w*64, w*64+64)
    f32x16 acc0 = {}; f32x16 acc1 = {};
    int nt0 = w*2, nt1 = w*2 + 1;
    const short8* A8 = reinterpret_cast<const short8*>(ehidF) + (size_t)te*512;
    const short8* B8 = reinterpret_cast<const short8*>(w2F);
    #pragma unroll
    for (int kt = 0; kt < 8; ++kt) {
        short8 a  = A8[kt*64 + l];
        short8 b0 = B8[(nt0*8 + kt)*64 + l];
        short8 b1 = B8[(nt1*8 + kt)*64 + l];
        acc0 = __builtin_amdgcn_mfma_f32_32x32x16_bf16(a, b0, acc0, 0, 0, 0);
        acc1 = __builtin_amdgcn_mfma_f32_32x32x16_bf16(a, b1, acc1, 0, 0, 0);
    }
    // ---- epilogue: +b2, cvt bf16, store to LDS. C/D layout (m101-verified):
    // col = lane&31, row = (reg&3) + 8*(reg>>2) + 4*(lane>>5)
    float bias0 = b2[nt0*32 + col];
    float bias1 = b2[nt1*32 + col];
    #pragma unroll
    for (int r = 0; r < 16; ++r) {
        int row = (r & 3) + 8*(r >> 2) + 4*hi;
        WeL[row*WEPITCH + nt0*32 + col] = f2bf(acc0[r] + bias0);
        WeL[row*WEPITCH + nt1*32 + col] = f2bf(acc1[r] + bias1);
    }
    __syncthreads();

    // ---- msg phase: edge eloc = w*2 + hi, lane handles output o = col
    int eloc = w*2 + hi;
    int e = te*32 + eloc;
    if (e < E) {
        int s = src[e];
        float vo = nodef[(size_t)s*D + col];
        float msg = 0.0f;
        const short* W = &WeL[eloc*WEPITCH];
        #pragma unroll
        for (int i = 0; i < D; ++i) {
            float vi = __shfl(vo, i, 32);
            msg += vi * bf2f(W[i*32 + col]);
        }
        atomicAdd(&agg[(size_t)dst[e]*D + col], msg);
    }
}

// ---------------- scatter-mean finish + root + relu + GRU (fp32) ----------------
__global__ __launch_bounds__(256) void k_gru(float* __restrict__ out,
    const float* __restrict__ agg, const float* __restrict__ invd,
    const float* __restrict__ root_w, const float* __restrict__ conv_b,
    const float* __restrict__ wih, const float* __restrict__ whh,
    const float* __restrict__ bih, const float* __restrict__ bhh, int n){
    __shared__ float srw[D*D];
    __shared__ float swihT[D*97];
    __shared__ float swhhT[D*97];
    __shared__ float scb[D], sbih[96], sbhh[96];
    int t = threadIdx.x;
    for (int idx = t; idx < D*D; idx += 256) srw[idx] = root_w[idx];
    for (int idx = t; idx < 96*D; idx += 256) { int j = idx/D, i = idx%D; swihT[i*97+j] = wih[idx]; }
    for (int idx = t; idx < 96*D; idx += 256) { int j = idx/D, i = idx%D; swhhT[i*97+j] = whh[idx]; }
    if (t < D) scb[t] = conv_b[t];
    if (t < 96) { sbih[t] = bih[t]; sbhh[t] = bhh[t]; }
    __syncthreads();
    int g = t >> 5, o = t & 31;
    int node = blockIdx.x*8 + g;
    if (node >= n) return;
    float ho = out[(size_t)node*D + o];
    float acc = agg[(size_t)node*D + o]*invd[node] + scb[o];
    #pragma unroll
    for (int i = 0; i < D; ++i) acc += __shfl(ho, i, 32)*srw[i*D + o];
    float m = fmaxf(acc, 0.0f);
    float gi0 = sbih[o], gi1 = sbih[o+32], gi2 = sbih[o+64];
    float gh0 = sbhh[o], gh1 = sbhh[o+32], gh2 = sbhh[o+64];
    #pragma unroll
    for (int i = 0; i < D; ++i) {
        float mi = __shfl(m, i, 32), hi = __shfl(ho, i, 32);
        gi0 += mi*swihT[i*97+o];    gh0 += hi*swhhT[i*97+o];
        gi1 += mi*swihT[i*97+o+32]; gh1 += hi*swhhT[i*97+o+32];
        gi2 += mi*swihT[i*97+o+64]; gh2 += hi*swhhT[i*97+o+64];
    }
    float r  = sigf(gi0+gh0);
    float z  = sigf(gi1+gh1);
    float ng = tanhf(gi2 + r*gh2);
    out[(size_t)node*D + o] = (1.0f - z)*ng + z*ho;
}

// ---------------- Set2Set (3 steps) + lin1/lin2 readout (fp64) ----------------
__global__ __launch_bounds__(64) void k_s2s(const float* __restrict__ out,
    const float* __restrict__ wihT, const float* __restrict__ whhT,
    const float* __restrict__ bih, const float* __restrict__ bhh,
    const float* __restrict__ l1T, const float* __restrict__ l1b,
    const float* __restrict__ l2w, const float* __restrict__ l2b,
    float* __restrict__ dpred, float* __restrict__ demb, int n, int ngr){
    int b = blockIdx.x, t = threadIdx.x;
    int start = (int)(((long long)b*n + ngr - 1)/ngr);
    int end   = (int)(((long long)(b+1)*n + ngr - 1)/ngr);
    if (end > n) end = n;
    int cnt = end - start;
    __shared__ double qs[2*D];
    __shared__ double hhv[D], ccv[D], qv[D];
    __shared__ double gate[4*D];
    __shared__ double ea[40];
    __shared__ double red[2];
    if (t < 2*D) qs[t] = 0.0;
    if (t < D) { hhv[t] = 0.0; ccv[t] = 0.0; }
    __syncthreads();
    for (int step = 0; step < 3; ++step) {
        double g1 = (double)bih[t] + (double)bhh[t];
        double g2 = (double)bih[t+64] + (double)bhh[t+64];
        for (int i = 0; i < 2*D; ++i) {
            double q = qs[i];
            g1 += q * (double)wihT[i*128 + t];
            g2 += q * (double)wihT[i*128 + t + 64];
        }
        for (int i = 0; i < D; ++i) {
            double h = hhv[i];
            g1 += h * (double)whhT[i*128 + t];
            g2 += h * (double)whhT[i*128 + t + 64];
        }
        gate[t] = g1; gate[t+64] = g2;
        __syncthreads();
        if (t < D) {
            double ig = dsig(gate[t]);
            double fg = dsig(gate[D+t]);
            double gg = tanh(gate[2*D+t]);
            double og = dsig(gate[3*D+t]);
            double c  = fg*ccv[t] + ig*gg;
            ccv[t] = c;
            double h = og*tanh(c);
            hhv[t] = h;
            qv[t]  = h;
        }
        __syncthreads();
        if (t < cnt) {
            const float* orow = out + (size_t)(start+t)*D;
            double e = 0.0;
            #pragma unroll
            for (int o = 0; o < D; ++o) e += (double)orow[o]*qv[o];
            ea[t] = e;
        }
        __syncthreads();
        if (t == 0) {
            double mx = -1e300;
            for (int i = 0; i < cnt; ++i) mx = fmax(mx, ea[i]);
            red[0] = mx;
        }
        __syncthreads();
        if (t < cnt) ea[t] = exp(ea[t] - red[0]);
        __syncthreads();
        if (t == 0) {
            double s = 0.0;
            for (int i = 0; i < cnt; ++i) s += ea[i];
            red[1] = s;
        }
        __syncthreads();
        if (t < cnt) ea[t] = ea[t]/red[1];
        __syncthreads();
        if (t < D) {
            double acc = 0.0;
            for (int i = 0; i < cnt; ++i) acc += ea[i]*(double)out[(size_t)(start+i)*D + t];
            qs[t]   = qv[t];
            qs[D+t] = acc;
        }
        __syncthreads();
    }
    double ge1 = l1b[t], ge2 = l1b[t+64];
    for (int i = 0; i < 2*D; ++i) {
        double q = qs[i];
        ge1 += q*(double)l1T[i*128 + t];
        ge2 += q*(double)l1T[i*128 + t + 64];
    }
    demb[(size_t)b*128 + t]      = (float)ge1;
    demb[(size_t)b*128 + t + 64] = (float)ge2;
    double p = fmax(ge1, 0.0)*(double)l2w[t] + fmax(ge2, 0.0)*(double)l2w[t+64];
    #pragma unroll
    for (int off = 32; off > 0; off >>= 1) {
        double other = __shfl_down(p, off, 64);
        p += other;
    }
    if (t == 0) dpred[b] = (float)(p + (double)l2b[0]);
}

extern "C" void kernel_launch(void* const* d_in, const int* in_sizes, int n_in,
                              void* d_out, int out_size, void* d_ws, size_t ws_size,
                              hipStream_t stream) {
    const float* x       = (const float*)d_in[0];
    const float* eattr   = (const float*)d_in[1];
    const float* lin0_w  = (const float*)d_in[2];
    const float* lin0_b  = (const float*)d_in[3];
    const float* enn_w1  = (const float*)d_in[4];
    const float* enn_b1  = (const float*)d_in[5];
    const float* enn_w2  = (const float*)d_in[6];
    const float* enn_b2  = (const float*)d_in[7];
    const float* root_w  = (const float*)d_in[8];
    const float* conv_b  = (const float*)d_in[9];
    const float* gru_wih = (const float*)d_in[10];
    const float* gru_whh = (const float*)d_in[11];
    const float* gru_bih = (const float*)d_in[12];
    const float* gru_bhh = (const float*)d_in[13];
    const float* lstm_wih= (const float*)d_in[14];
    const float* lstm_whh= (const float*)d_in[15];
    const float* lstm_bih= (const float*)d_in[16];
    const float* lstm_bhh= (const float*)d_in[17];
    const float* lin1_w  = (const float*)d_in[18];
    const float* lin1_b  = (const float*)d_in[19];
    const float* lin2_w  = (const float*)d_in[20];
    const float* lin2_b  = (const float*)d_in[21];
    const int*   eidx    = (const int*)d_in[22];

    int N = in_sizes[0]/FIN;     // 100000
    int E = in_sizes[1]/3;       // 300000
    int B = 4096;
    const int* src = eidx;
    const int* dst = eidx + E;
    int nte = (E + 31) / 32;     // 9375

    char* ws = (char*)d_ws;
    size_t off = 0;
    auto alloc = [&](size_t bytes)->void* {
        void* p = ws + off; off += (bytes + 255) & ~(size_t)255; return p;
    };
    float* outb  = (float*)alloc((size_t)N*D*sizeof(float));       // 12.8 MB
    float* agg   = (float*)alloc((size_t)N*D*sizeof(float));       // 12.8 MB
    float* invd  = (float*)alloc((size_t)N*sizeof(float));
    int*   deg   = (int*)  alloc((size_t)N*sizeof(int));
    float* wihT  = (float*)alloc((size_t)128*64*sizeof(float));
    float* whhT  = (float*)alloc((size_t)128*32*sizeof(float));
    float* l1T   = (float*)alloc((size_t)128*64*sizeof(float));
    short* ehidF = (short*)alloc((size_t)nte*512*8*sizeof(short)); // 76.8 MB
    short* w2F   = (short*)alloc((size_t)32*8*64*8*sizeof(short)); // 256 KB
    (void)ws_size; (void)n_in; (void)out_size;                     // total ~104 MB < 256 MiB

    hipMemsetAsync(deg, 0, (size_t)N*sizeof(int), stream);
    k_deg<<<(E+255)/256, 256, 0, stream>>>(dst, deg, E);
    k_invdeg<<<(N+255)/256, 256, 0, stream>>>(deg, invd, N);
    k_tposew<<<32, 256, 0, stream>>>(lstm_wih, lstm_whh, lin1_w, wihT, whhT, l1T);
    k_lin0<<<(N+7)/8, 256, 0, stream>>>(x, lin0_w, lin0_b, outb, N);
    k_ehidf<<<(nte*512+255)/256, 256, 0, stream>>>(eattr, enn_w1, enn_b1, ehidF, E, nte);
    k_w2f<<<64, 256, 0, stream>>>(enn_w2, w2F);

    for (int it = 0; it < 3; ++it) {
        hipMemsetAsync(agg, 0, (size_t)N*D*sizeof(float), stream);
        k_fused<<<nte, 1024, 0, stream>>>(ehidF, w2F, enn_b2, outb, src, dst, agg, E);
        k_gru<<<(N+7)/8, 256, 0, stream>>>(outb, agg, invd, root_w, conv_b,
                                           gru_wih, gru_whh, gru_bih, gru_bhh, N);
    }

    float* dpred = (float*)d_out;
    float* demb  = (float*)d_out + B;
    k_s2s<<<B, 64, 0, stream>>>(outb, wihT, whhT, lstm_bih, lstm_bhh,
                                l1T, lin1_b, lin2_w, lin2_b, dpred, demb, N, B);
}